// Round 10
// baseline (334.839 us; speedup 1.0000x reference)
//
#include <hip/hip_runtime.h>
#include <math.h>

#define F 64
#define NPB 160        // nodes per bucket
#define STAGE_CAP 6304 // staged CSR entries per bucket (mean ~2720, +60 sigma)

typedef __attribute__((ext_vector_type(8))) short bf16x8;
typedef __attribute__((ext_vector_type(4))) float f32x4;

__device__ inline unsigned short f2bf(float f) {
  unsigned int u = __float_as_uint(f);
  u += 0x7fffu + ((u >> 16) & 1u);   // round-to-nearest-even
  return (unsigned short)(u >> 16);
}

// ---------------- bucketed CSR build ----------------

__global__ __launch_bounds__(256) void k_bin_count(const int* __restrict__ edst, int* __restrict__ cntT,
                                                   int e, int ch, int nblk, int nb) {
  __shared__ int h[1024];
  int k = blockIdx.x, tid = threadIdx.x;
  for (int i = tid; i < nb; i += 256) h[i] = 0;
  __syncthreads();
  int beg = k * ch, end = min(e, beg + ch);
  for (int i = beg + tid; i < end; i += 256) atomicAdd(&h[edst[i] / NPB], 1);
  __syncthreads();
  for (int b = tid; b < nb; b += 256) cntT[b * nblk + k] = h[b];
}

// per-256-block exclusive scan; block totals to bsums (global offset = posT[i] + bsums[i>>8])
__global__ __launch_bounds__(256) void k_scan1(const int* __restrict__ counts, int* __restrict__ offs,
                                               int* __restrict__ bsums, int n) {
  int tid = threadIdx.x, lane = tid & 63, wv = tid >> 6;
  int i = blockIdx.x * 256 + tid;
  int v = (i < n) ? counts[i] : 0;
  int x = v;
  #pragma unroll
  for (int o = 1; o <= 32; o <<= 1) { int y = __shfl_up(x, o); if (lane >= o) x += y; }
  __shared__ int wsum[4];
  if (lane == 63) wsum[wv] = x;
  __syncthreads();
  int add = 0;
  for (int w = 0; w < wv; w++) add += wsum[w];
  int incl = x + add;
  if (i < n) offs[i] = incl - v;
  if (tid == 255) bsums[blockIdx.x] = incl;
}

// single-block scan of block sums; also zeroes degree histogram + cursors
__global__ __launch_bounds__(256) void k_scan2(int* __restrict__ bs, int nb,
                                               int* __restrict__ dh, int* __restrict__ dcur) {
  __shared__ int wsum[4];
  __shared__ int carry_sh;
  int tid = threadIdx.x, lane = tid & 63, wv = tid >> 6;
  if (tid < 64) { dh[tid] = 0; dcur[tid] = 0; }
  if (tid == 0) carry_sh = 0;
  __syncthreads();
  for (int base = 0; base < nb; base += 256) {
    int i = base + tid;
    int v = (i < nb) ? bs[i] : 0;
    int x = v;
    #pragma unroll
    for (int o = 1; o <= 32; o <<= 1) { int y = __shfl_up(x, o); if (lane >= o) x += y; }
    if (lane == 63) wsum[wv] = x;
    __syncthreads();
    int add = 0;
    for (int w = 0; w < wv; w++) add += wsum[w];
    int incl = x + add;
    int carry = carry_sh;
    if (i < nb) bs[i] = incl - v + carry;
    __syncthreads();
    if (tid == 255) carry_sh = carry + incl;
    __syncthreads();
  }
}

__global__ __launch_bounds__(256) void k_bin_scatter(const int* __restrict__ esrc, const int* __restrict__ edst,
                                                     const int* __restrict__ posT, const int* __restrict__ bsums,
                                                     unsigned int* __restrict__ binned,
                                                     int e, int ch, int nblk, int nb) {
  __shared__ int cur[1024];
  int k = blockIdx.x, tid = threadIdx.x;
  for (int b = tid; b < nb; b += 256) {
    int idx = b * nblk + k;
    cur[b] = posT[idx] + bsums[idx >> 8];
  }
  __syncthreads();
  int beg = k * ch, end = min(e, beg + ch);
  for (int i = beg + tid; i < end; i += 256) {
    int d = edst[i];
    int b = d / NPB;
    unsigned int ld = (unsigned int)(d - b * NPB);
    int p = atomicAdd(&cur[b], 1);
    binned[p] = (unsigned int)esrc[i] | (ld << 24);
  }
}

// one block per bucket: build CSR rows (self-loop at row head), emit ssrc + offs + degree hist
__global__ __launch_bounds__(256) void k_bucket_csr(const unsigned int* __restrict__ binned,
                                                    const int* __restrict__ posT, const int* __restrict__ bsums,
                                                    int* __restrict__ ssrc, int* __restrict__ offs,
                                                    int* __restrict__ dh,
                                                    int n, int nblk, int nb, int e) {
  __shared__ int ncnt[NPB];
  __shared__ int noff[NPB];
  __shared__ int cur[NPB];
  __shared__ int sc[256];
  __shared__ int stage[STAGE_CAP];
  int b = blockIdx.x, tid = threadIdx.x;
  int node0 = b * NPB;
  int nn = min(NPB, n - node0);
  int i0 = b * nblk;
  int ebeg = posT[i0] + bsums[i0 >> 8];
  int eend;
  if (b == nb - 1) eend = e;
  else { int i1 = (b + 1) * nblk; eend = posT[i1] + bsums[i1 >> 8]; }
  int ecnt = eend - ebeg;
  for (int i = tid; i < NPB; i += 256) ncnt[i] = 0;
  __syncthreads();
  for (int i = tid; i < ecnt; i += 256) { unsigned int v = binned[ebeg + i]; atomicAdd(&ncnt[v >> 24], 1); }
  __syncthreads();
  int x = (tid < nn) ? ncnt[tid] + 1 : 0;
  sc[tid] = x;
  __syncthreads();
  #pragma unroll
  for (int o = 1; o < 256; o <<= 1) {
    int y = (tid >= o) ? sc[tid - o] : 0;
    __syncthreads();
    sc[tid] += y;
    __syncthreads();
  }
  if (tid < nn) noff[tid] = sc[tid] - x;
  __syncthreads();
  int tot = ecnt + nn;
  int outbase = ebeg + node0;
  bool staged = (tot <= STAGE_CAP);
  if (tid < nn) {
    cur[tid] = noff[tid] + 1;
    offs[node0 + tid] = outbase + noff[tid];
    if (staged) stage[noff[tid]] = node0 + tid;
    else        ssrc[outbase + noff[tid]] = node0 + tid;
  }
  __syncthreads();
  if (staged) {
    for (int i = tid; i < ecnt; i += 256) {
      unsigned int v = binned[ebeg + i];
      int p = atomicAdd(&cur[v >> 24], 1);
      stage[p] = (int)(v & 0xFFFFFFu);
    }
    __syncthreads();
    for (int i = tid; i < tot; i += 256) ssrc[outbase + i] = stage[i];
  } else {
    for (int i = tid; i < ecnt; i += 256) {
      unsigned int v = binned[ebeg + i];
      int p = atomicAdd(&cur[v >> 24], 1);
      ssrc[outbase + p] = (int)(v & 0xFFFFFFu);
    }
  }
  if (b == 0 && tid == 0) offs[n] = e + n;
  // fused degree histogram (64 bins); sc[] is dead, ncnt intact
  __syncthreads();
  if (tid < 64) sc[tid] = 0;
  __syncthreads();
  if (tid < nn) atomicAdd(&sc[min(ncnt[tid] + 1, 63)], 1);
  __syncthreads();
  if (tid < 64 && sc[tid]) atomicAdd(&dh[tid], sc[tid]);
}

// ---------------- degree-sorted order (descending) + out init, no separate base pass ----------------
__global__ __launch_bounds__(256) void k_degscatter(const int* __restrict__ offs, const int* __restrict__ dh,
                                                    int* __restrict__ dcur, int* __restrict__ order,
                                                    float* __restrict__ out, const float* __restrict__ bo,
                                                    int n, int ng) {
  __shared__ int h[64];
  __shared__ int base[64];
  __shared__ int sbase[64];
  int tid = threadIdx.x;
  for (int i = blockIdx.x * 256 + tid; i < ng; i += gridDim.x * 256) out[i] = bo[0];
  if (tid < 64) {
    h[tid] = 0;
    int acc = 0;
    for (int b = 63; b > tid; b--) acc += dh[b];   // descending-degree global base
    sbase[tid] = acc;
  }
  __syncthreads();
  int i = blockIdx.x * 256 + tid;
  int bin = 0, rank = 0;
  if (i < n) { int d = offs[i + 1] - offs[i]; bin = min(d, 63); rank = atomicAdd(&h[bin], 1); }
  __syncthreads();
  if (tid < 64 && h[tid]) base[tid] = atomicAdd(&dcur[tid], h[tid]);
  __syncthreads();
  if (i < n) order[sbase[bin] + base[bin] + rank] = i;
}

// ---------------- MFMA GEMM h = in @ W (64x64): bf16 h out, fp32 al_src/al_dst ----------------
template<bool IN_BF16>
__global__ __launch_bounds__(256) void k_gemm(const void* __restrict__ in, const float* __restrict__ W,
                                              const float* __restrict__ avs, const float* __restrict__ avd,
                                              unsigned short* __restrict__ hgb, float* __restrict__ als,
                                              float* __restrict__ ald, int n) {
  int tid = threadIdx.x, lane = tid & 63, wv = tid >> 6;
  int l15 = lane & 15, quad = lane >> 4;
  bf16x8 bfr[4][2];
  #pragma unroll
  for (int c = 0; c < 4; c++) {
    #pragma unroll
    for (int kk = 0; kk < 2; kk++) {
      #pragma unroll
      for (int j = 0; j < 8; j++) {
        int k = kk * 32 + quad * 8 + j;
        bfr[c][kk][j] = (short)f2bf(W[k * F + c * 16 + l15]);
      }
    }
  }
  float as_l[4], ad_l[4];
  #pragma unroll
  for (int c = 0; c < 4; c++) { as_l[c] = avs[c * 16 + l15]; ad_l[c] = avd[c * 16 + l15]; }

  int nchunks = n >> 6;
  for (int chunk = blockIdx.x; chunk < nchunks; chunk += gridDim.x) {
    int r0 = (chunk << 6) + (wv << 4);
    bf16x8 a0, a1;
    if constexpr (IN_BF16) {
      const uint4* row4 = (const uint4*)((const unsigned short*)in + (size_t)(r0 + l15) * F);
      uint4 u0 = row4[quad];
      uint4 u1 = row4[quad + 4];
      a0 = *(const bf16x8*)&u0;
      a1 = *(const bf16x8*)&u1;
    } else {
      const float4* xr = (const float4*)((const float*)in + (size_t)(r0 + l15) * F + quad * 8);
      float4 xa = xr[0], xb = xr[1];
      float4 xc = xr[8], xd = xr[9];
      a0[0] = (short)f2bf(xa.x); a0[1] = (short)f2bf(xa.y); a0[2] = (short)f2bf(xa.z); a0[3] = (short)f2bf(xa.w);
      a0[4] = (short)f2bf(xb.x); a0[5] = (short)f2bf(xb.y); a0[6] = (short)f2bf(xb.z); a0[7] = (short)f2bf(xb.w);
      a1[0] = (short)f2bf(xc.x); a1[1] = (short)f2bf(xc.y); a1[2] = (short)f2bf(xc.z); a1[3] = (short)f2bf(xc.w);
      a1[4] = (short)f2bf(xd.x); a1[5] = (short)f2bf(xd.y); a1[6] = (short)f2bf(xd.z); a1[7] = (short)f2bf(xd.w);
    }
    f32x4 cfr[4];
    #pragma unroll
    for (int c = 0; c < 4; c++) {
      cfr[c] = (f32x4){0.f, 0.f, 0.f, 0.f};
      cfr[c] = __builtin_amdgcn_mfma_f32_16x16x32_bf16(a0, bfr[c][0], cfr[c], 0, 0, 0);
      cfr[c] = __builtin_amdgcn_mfma_f32_16x16x32_bf16(a1, bfr[c][1], cfr[c], 0, 0, 0);
    }
    #pragma unroll
    for (int i = 0; i < 4; i++) {
      int row = r0 + quad * 4 + i;
      #pragma unroll
      for (int c = 0; c < 4; c++) hgb[(size_t)row * F + c * 16 + l15] = f2bf(cfr[c][i]);
      float ps = cfr[0][i] * as_l[0] + cfr[1][i] * as_l[1] + cfr[2][i] * as_l[2] + cfr[3][i] * as_l[3];
      float pd = cfr[0][i] * ad_l[0] + cfr[1][i] * ad_l[1] + cfr[2][i] * ad_l[2] + cfr[3][i] * ad_l[3];
      #pragma unroll
      for (int o = 1; o <= 8; o <<= 1) { ps += __shfl_xor(ps, o); pd += __shfl_xor(pd, o); }
      if (l15 == 0) { als[row] = ps; ald[row] = pd; }
    }
  }
}

// ---------------- fused softmax+SpMM, node-per-subgroup, 8-edge chunk staging ----------------
// Stage: subgroup's 8 lanes handle 8 edges (coalesced ssrc, 64-wide als gather, one v_exp/64 edges),
// park (src<<3, ex) in LDS. Consume: per edge one broadcast ds_read_b64 + one dwordx4 row + 16 FMA.
// MODE 0: write bf16 rows (layer 1).  MODE 1: fused readout dot with Wout + atomicAdd (layer 2).
template<int MODE>
__global__ __launch_bounds__(256) void k_spmm(const int* __restrict__ offs, const int* __restrict__ ssrc,
                                              const int* __restrict__ order,
                                              const unsigned short* __restrict__ hgb,
                                              const float* __restrict__ als, const float* __restrict__ ald,
                                              const float* __restrict__ bias, const float* __restrict__ Wout,
                                              void* __restrict__ outp, int n) {
  __shared__ int2 st[4][64];
  int tid = threadIdx.x, lane = tid & 63, wv = tid >> 6;
  int g8 = lane >> 3, l8 = lane & 7;
  const uint4* hg4 = (const uint4*)hgb;
  float4 bl0 = ((const float4*)bias)[l8 * 2];
  float4 bl1 = ((const float4*)bias)[l8 * 2 + 1];

  int idx = (blockIdx.x * 4 + wv) * 8 + g8;
  int cidx = min(idx, n - 1);
  bool nodeok = idx < n;
  int node = order[cidx];
  int beg = offs[node];
  int deg = nodeok ? (offs[node + 1] - beg) : 0;
  int degc = max(deg - 1, 0);
  float aldv = ald[node];

  int dm = deg;
  #pragma unroll
  for (int o = 8; o <= 32; o <<= 1) dm = max(dm, __shfl_xor(dm, o));

  float s = 0.f;
  float acc[8];
  #pragma unroll
  for (int k = 0; k < 8; k++) acc[k] = 0.f;

  for (int c0 = 0; c0 < dm; c0 += 8) {
    // stage: lane l8 owns edge c0+l8 of its subgroup's node
    int j = c0 + l8;
    int src = ssrc[beg + min(j, degc)];
    float t = als[src] + aldv;
    t = fmaxf(t, 0.2f * t);                    // leaky_relu 0.2
    float ex = (j < deg) ? __expf(t) : 0.f;
    s += ex;
    st[wv][lane] = make_int2(src << 3, __float_as_int(ex));
    // consume (wave-uniform bound; same-wave DS ordering, no barrier)
    int m8 = dm - c0;
    if (m8 >= 8) {
      #pragma unroll
      for (int j2 = 0; j2 < 8; j2++) {
        int2 pv = st[wv][(g8 << 3) + j2];
        float w = __int_as_float(pv.y);
        uint4 u = hg4[(size_t)pv.x + l8];
        acc[0] = fmaf(w, __uint_as_float(u.x << 16), acc[0]);
        acc[1] = fmaf(w, __uint_as_float(u.x & 0xffff0000u), acc[1]);
        acc[2] = fmaf(w, __uint_as_float(u.y << 16), acc[2]);
        acc[3] = fmaf(w, __uint_as_float(u.y & 0xffff0000u), acc[3]);
        acc[4] = fmaf(w, __uint_as_float(u.z << 16), acc[4]);
        acc[5] = fmaf(w, __uint_as_float(u.z & 0xffff0000u), acc[5]);
        acc[6] = fmaf(w, __uint_as_float(u.w << 16), acc[6]);
        acc[7] = fmaf(w, __uint_as_float(u.w & 0xffff0000u), acc[7]);
      }
    } else {
      for (int j2 = 0; j2 < m8; j2++) {
        int2 pv = st[wv][(g8 << 3) + j2];
        float w = __int_as_float(pv.y);
        uint4 u = hg4[(size_t)pv.x + l8];
        acc[0] = fmaf(w, __uint_as_float(u.x << 16), acc[0]);
        acc[1] = fmaf(w, __uint_as_float(u.x & 0xffff0000u), acc[1]);
        acc[2] = fmaf(w, __uint_as_float(u.y << 16), acc[2]);
        acc[3] = fmaf(w, __uint_as_float(u.y & 0xffff0000u), acc[3]);
        acc[4] = fmaf(w, __uint_as_float(u.z << 16), acc[4]);
        acc[5] = fmaf(w, __uint_as_float(u.z & 0xffff0000u), acc[5]);
        acc[6] = fmaf(w, __uint_as_float(u.w << 16), acc[6]);
        acc[7] = fmaf(w, __uint_as_float(u.w & 0xffff0000u), acc[7]);
      }
    }
  }

  // subgroup sum of s (lanes hold disjoint partials)
  #pragma unroll
  for (int o = 1; o <= 4; o <<= 1) s += __shfl_xor(s, o);

  if (!nodeok) return;
  float iv = 1.f / (s + 1e-16f);
  float r[8];
  r[0] = fmaxf(fmaf(acc[0], iv, bl0.x), 0.f);
  r[1] = fmaxf(fmaf(acc[1], iv, bl0.y), 0.f);
  r[2] = fmaxf(fmaf(acc[2], iv, bl0.z), 0.f);
  r[3] = fmaxf(fmaf(acc[3], iv, bl0.w), 0.f);
  r[4] = fmaxf(fmaf(acc[4], iv, bl1.x), 0.f);
  r[5] = fmaxf(fmaf(acc[5], iv, bl1.y), 0.f);
  r[6] = fmaxf(fmaf(acc[6], iv, bl1.z), 0.f);
  r[7] = fmaxf(fmaf(acc[7], iv, bl1.w), 0.f);
  if constexpr (MODE == 0) {
    unsigned short p[8];
    #pragma unroll
    for (int k = 0; k < 8; k++) p[k] = f2bf(r[k]);
    ((uint4*)outp)[(size_t)node * 8 + l8] = *(const uint4*)p;
  } else {
    int grp = node / 20, slot = node - grp * 20;
    const float* wr = Wout + slot * F + l8 * 8;
    float dot = 0.f;
    #pragma unroll
    for (int k = 0; k < 8; k++) dot = fmaf(r[k], wr[k], dot);
    #pragma unroll
    for (int o = 1; o <= 4; o <<= 1) dot += __shfl_xor(dot, o);
    if (l8 == 0) atomicAdd((float*)outp + grp, dot);
  }
}

// ---------------- launch ----------------
extern "C" void kernel_launch(void* const* d_in, const int* in_sizes, int n_in,
                              void* d_out, int out_size, void* d_ws, size_t ws_size,
                              hipStream_t stream) {
  const float* x   = (const float*)d_in[0];
  const int*   ei  = (const int*)d_in[1];
  const float* W1  = (const float*)d_in[2];
  const float* as1 = (const float*)d_in[3];
  const float* ad1 = (const float*)d_in[4];
  const float* b1  = (const float*)d_in[5];
  const float* W2  = (const float*)d_in[6];
  const float* as2 = (const float*)d_in[7];
  const float* ad2 = (const float*)d_in[8];
  const float* b2  = (const float*)d_in[9];
  const float* Wo  = (const float*)d_in[10];
  const float* bo  = (const float*)d_in[11];
  float* out = (float*)d_out;

  const int N = in_sizes[0] / F;
  const int E = in_sizes[1] / 2;
  const int* esrc = ei;
  const int* edst = ei + E;

  size_t off = 0;
  auto alloc = [&](size_t bytes) -> void* {
    void* p = (char*)d_ws + off;
    off += (bytes + 255) & ~(size_t)255;
    return p;
  };
  float* A    = (float*)alloc((size_t)N * F * 4);           // A1 bf16; CSR cnt/pos scratch aliases head
  unsigned short* hgb = (unsigned short*)alloc((size_t)N * F * 2);  // bf16 gemm outputs; binned aliases head
  float* als  = (float*)alloc((size_t)N * 4);
  float* ald  = (float*)alloc((size_t)N * 4);
  int* offs   = (int*)alloc((size_t)(N + 1) * 4);
  int* bsums  = (int*)alloc(8192);
  int* ssrc   = (int*)alloc((size_t)(E + N) * 4);           // CSR src lists
  int* order  = (int*)alloc((size_t)N * 4);                 // degree-sorted node order
  int* dh     = (int*)alloc(256);                           // 64-bin degree histogram
  int* dcur   = (int*)alloc(256);                           // rank cursors (zeroed in scan2)
  (void)ws_size; (void)n_in; (void)out_size;

  const int NBLK = 256;
  const int NB = (N + NPB - 1) / NPB;
  const int CH = (E + NBLK - 1) / NBLK;
  const int FLAT = NB * NBLK;

  int* cntT = (int*)A;
  int* posT = (int*)((char*)A + ((size_t)FLAT * 4 + 1024));
  unsigned int* binned = (unsigned int*)hgb;

  int gF = (FLAT + 255) / 256;
  int gN = (N + 255) / 256;

  // CSR build: bucketed counting sort (dst-major), self-loop at row head
  k_bin_count<<<NBLK, 256, 0, stream>>>(edst, cntT, E, CH, NBLK, NB);
  k_scan1<<<gF, 256, 0, stream>>>(cntT, posT, bsums, FLAT);
  k_scan2<<<1, 256, 0, stream>>>(bsums, gF, dh, dcur);
  k_bin_scatter<<<NBLK, 256, 0, stream>>>(esrc, edst, posT, bsums, binned, E, CH, NBLK, NB);
  k_bucket_csr<<<NB, 256, 0, stream>>>(binned, posT, bsums, ssrc, offs, dh, N, NBLK, NB, E);

  // degree-sorted order (descending) + out init
  int NG = N / 20;
  k_degscatter<<<gN, 256, 0, stream>>>(offs, dh, dcur, order, out, bo, N, NG);

  int gSp = (N + 31) / 32;
  // layer 1
  k_gemm<false><<<2560, 256, 0, stream>>>(x, W1, as1, ad1, hgb, als, ald, N);
  k_spmm<0><<<gSp, 256, 0, stream>>>(offs, ssrc, order, hgb, als, ald, b1, nullptr, A, N);
  // layer 2 (reads bf16 A1) + fused readout
  k_gemm<true><<<2560, 256, 0, stream>>>(A, W2, as2, ad2, hgb, als, ald, N);
  k_spmm<1><<<gSp, 256, 0, stream>>>(offs, ssrc, order, hgb, als, ald, b2, Wo, out, N);
}

// Round 11
// 319.622 us; speedup vs baseline: 1.0476x; 1.0476x over previous
//
#include <hip/hip_runtime.h>
#include <math.h>

#define F 64
#define NPB 160        // nodes per bucket
#define STAGE_CAP 6304 // staged CSR entries per bucket (mean ~2720, +60 sigma)

typedef __attribute__((ext_vector_type(8))) short bf16x8;
typedef __attribute__((ext_vector_type(4))) float f32x4;

__device__ inline unsigned short f2bf(float f) {
  unsigned int u = __float_as_uint(f);
  u += 0x7fffu + ((u >> 16) & 1u);   // round-to-nearest-even
  return (unsigned short)(u >> 16);
}

// ---------------- bucketed CSR build (+ W fragment prep in extra block) ----------------

__global__ __launch_bounds__(256) void k_bin_count(const int* __restrict__ edst, int* __restrict__ cntT,
                                                   int e, int ch, int nblk, int nb,
                                                   const float* __restrict__ W1, const float* __restrict__ W2,
                                                   uint4* __restrict__ wf) {
  __shared__ int h[1024];
  int k = blockIdx.x, tid = threadIdx.x;
  if (k == nblk) {
    // pack W1/W2 into MFMA B-fragment layout: wf[layer*512 + (c*2+kk)*64 + lane] = 8 bf16 (j=0..7)
    for (int i = tid; i < 1024; i += 256) {
      int layer = i >> 9, rem = i & 511;
      int cb = rem >> 6, lane = rem & 63;
      int c = cb >> 1, kk = cb & 1;
      int l15 = lane & 15, quad = lane >> 4;
      const float* W = layer ? W2 : W1;
      unsigned short p[8];
      #pragma unroll
      for (int j = 0; j < 8; j++) {
        int kd = kk * 32 + quad * 8 + j;
        p[j] = f2bf(W[kd * F + c * 16 + l15]);
      }
      wf[i] = *(const uint4*)p;
    }
    return;
  }
  for (int i = tid; i < nb; i += 256) h[i] = 0;
  __syncthreads();
  int beg = k * ch, end = min(e, beg + ch);
  for (int i = beg + tid; i < end; i += 256) atomicAdd(&h[edst[i] / NPB], 1);
  __syncthreads();
  for (int b = tid; b < nb; b += 256) cntT[b * nblk + k] = h[b];
}

// per-256-block exclusive scan; block totals to bsums (global offset = posT[i] + bsums[i>>8])
__global__ __launch_bounds__(256) void k_scan1(const int* __restrict__ counts, int* __restrict__ offs,
                                               int* __restrict__ bsums, int n) {
  int tid = threadIdx.x, lane = tid & 63, wv = tid >> 6;
  int i = blockIdx.x * 256 + tid;
  int v = (i < n) ? counts[i] : 0;
  int x = v;
  #pragma unroll
  for (int o = 1; o <= 32; o <<= 1) { int y = __shfl_up(x, o); if (lane >= o) x += y; }
  __shared__ int wsum[4];
  if (lane == 63) wsum[wv] = x;
  __syncthreads();
  int add = 0;
  for (int w = 0; w < wv; w++) add += wsum[w];
  int incl = x + add;
  if (i < n) offs[i] = incl - v;
  if (tid == 255) bsums[blockIdx.x] = incl;
}

// single-block scan of block sums; also initializes out[] = b_out
__global__ __launch_bounds__(256) void k_scan2(int* __restrict__ bs, int nb,
                                               float* __restrict__ out, const float* __restrict__ bo, int ng) {
  __shared__ int wsum[4];
  __shared__ int carry_sh;
  int tid = threadIdx.x, lane = tid & 63, wv = tid >> 6;
  float b0 = bo[0];
  for (int i = tid; i < ng; i += 256) out[i] = b0;
  if (tid == 0) carry_sh = 0;
  __syncthreads();
  for (int base = 0; base < nb; base += 256) {
    int i = base + tid;
    int v = (i < nb) ? bs[i] : 0;
    int x = v;
    #pragma unroll
    for (int o = 1; o <= 32; o <<= 1) { int y = __shfl_up(x, o); if (lane >= o) x += y; }
    if (lane == 63) wsum[wv] = x;
    __syncthreads();
    int add = 0;
    for (int w = 0; w < wv; w++) add += wsum[w];
    int incl = x + add;
    int carry = carry_sh;
    if (i < nb) bs[i] = incl - v + carry;
    __syncthreads();
    if (tid == 255) carry_sh = carry + incl;
    __syncthreads();
  }
}

__global__ __launch_bounds__(256) void k_bin_scatter(const int* __restrict__ esrc, const int* __restrict__ edst,
                                                     const int* __restrict__ posT, const int* __restrict__ bsums,
                                                     unsigned int* __restrict__ binned,
                                                     int e, int ch, int nblk, int nb) {
  __shared__ int cur[1024];
  int k = blockIdx.x, tid = threadIdx.x;
  for (int b = tid; b < nb; b += 256) {
    int idx = b * nblk + k;
    cur[b] = posT[idx] + bsums[idx >> 8];
  }
  __syncthreads();
  int beg = k * ch, end = min(e, beg + ch);
  for (int i = beg + tid; i < end; i += 256) {
    int d = edst[i];
    int b = d / NPB;
    unsigned int ld = (unsigned int)(d - b * NPB);
    int p = atomicAdd(&cur[b], 1);
    binned[p] = (unsigned int)esrc[i] | (ld << 24);
  }
}

// one block per bucket: build CSR rows (self-loop at row head), emit ssrc + offs
__global__ __launch_bounds__(256) void k_bucket_csr(const unsigned int* __restrict__ binned,
                                                    const int* __restrict__ posT, const int* __restrict__ bsums,
                                                    int* __restrict__ ssrc, int* __restrict__ offs,
                                                    int n, int nblk, int nb, int e) {
  __shared__ int ncnt[NPB];
  __shared__ int noff[NPB];
  __shared__ int cur[NPB];
  __shared__ int sc[256];
  __shared__ int stage[STAGE_CAP];
  int b = blockIdx.x, tid = threadIdx.x;
  int node0 = b * NPB;
  int nn = min(NPB, n - node0);
  int i0 = b * nblk;
  int ebeg = posT[i0] + bsums[i0 >> 8];
  int eend;
  if (b == nb - 1) eend = e;
  else { int i1 = (b + 1) * nblk; eend = posT[i1] + bsums[i1 >> 8]; }
  int ecnt = eend - ebeg;
  for (int i = tid; i < NPB; i += 256) ncnt[i] = 0;
  __syncthreads();
  for (int i = tid; i < ecnt; i += 256) { unsigned int v = binned[ebeg + i]; atomicAdd(&ncnt[v >> 24], 1); }
  __syncthreads();
  int x = (tid < nn) ? ncnt[tid] + 1 : 0;
  sc[tid] = x;
  __syncthreads();
  #pragma unroll
  for (int o = 1; o < 256; o <<= 1) {
    int y = (tid >= o) ? sc[tid - o] : 0;
    __syncthreads();
    sc[tid] += y;
    __syncthreads();
  }
  if (tid < nn) noff[tid] = sc[tid] - x;
  __syncthreads();
  int tot = ecnt + nn;
  int outbase = ebeg + node0;
  bool staged = (tot <= STAGE_CAP);
  if (tid < nn) {
    cur[tid] = noff[tid] + 1;
    offs[node0 + tid] = outbase + noff[tid];
    if (staged) stage[noff[tid]] = node0 + tid;
    else        ssrc[outbase + noff[tid]] = node0 + tid;
  }
  __syncthreads();
  if (staged) {
    for (int i = tid; i < ecnt; i += 256) {
      unsigned int v = binned[ebeg + i];
      int p = atomicAdd(&cur[v >> 24], 1);
      stage[p] = (int)(v & 0xFFFFFFu);
    }
    __syncthreads();
    for (int i = tid; i < tot; i += 256) ssrc[outbase + i] = stage[i];
  } else {
    for (int i = tid; i < ecnt; i += 256) {
      unsigned int v = binned[ebeg + i];
      int p = atomicAdd(&cur[v >> 24], 1);
      ssrc[outbase + p] = (int)(v & 0xFFFFFFu);
    }
  }
  if (b == 0 && tid == 0) offs[n] = e + n;
}

// ---------------- MFMA GEMM h = in @ W (64x64): bf16 h out, fp32 al_src/al_dst ----------------
// W fragments pre-packed (wf): prologue = 8 coalesced dwordx4 loads instead of 64 strided loads.
template<bool IN_BF16>
__global__ __launch_bounds__(256) void k_gemm(const void* __restrict__ in, const uint4* __restrict__ wf,
                                              const float* __restrict__ avs, const float* __restrict__ avd,
                                              unsigned short* __restrict__ hgb, float* __restrict__ als,
                                              float* __restrict__ ald, int n) {
  int tid = threadIdx.x, lane = tid & 63, wv = tid >> 6;
  int l15 = lane & 15, quad = lane >> 4;
  bf16x8 bfr[4][2];
  #pragma unroll
  for (int cb = 0; cb < 8; cb++) {
    uint4 u = wf[cb * 64 + lane];
    bfr[cb >> 1][cb & 1] = *(const bf16x8*)&u;
  }
  float as_l[4], ad_l[4];
  #pragma unroll
  for (int c = 0; c < 4; c++) { as_l[c] = avs[c * 16 + l15]; ad_l[c] = avd[c * 16 + l15]; }

  int nchunks = n >> 6;
  for (int chunk = blockIdx.x; chunk < nchunks; chunk += gridDim.x) {
    int r0 = (chunk << 6) + (wv << 4);
    bf16x8 a0, a1;
    if constexpr (IN_BF16) {
      const uint4* row4 = (const uint4*)((const unsigned short*)in + (size_t)(r0 + l15) * F);
      uint4 u0 = row4[quad];
      uint4 u1 = row4[quad + 4];
      a0 = *(const bf16x8*)&u0;
      a1 = *(const bf16x8*)&u1;
    } else {
      const float4* xr = (const float4*)((const float*)in + (size_t)(r0 + l15) * F + quad * 8);
      float4 xa = xr[0], xb = xr[1];
      float4 xc = xr[8], xd = xr[9];
      a0[0] = (short)f2bf(xa.x); a0[1] = (short)f2bf(xa.y); a0[2] = (short)f2bf(xa.z); a0[3] = (short)f2bf(xa.w);
      a0[4] = (short)f2bf(xb.x); a0[5] = (short)f2bf(xb.y); a0[6] = (short)f2bf(xb.z); a0[7] = (short)f2bf(xb.w);
      a1[0] = (short)f2bf(xc.x); a1[1] = (short)f2bf(xc.y); a1[2] = (short)f2bf(xc.z); a1[3] = (short)f2bf(xc.w);
      a1[4] = (short)f2bf(xd.x); a1[5] = (short)f2bf(xd.y); a1[6] = (short)f2bf(xd.z); a1[7] = (short)f2bf(xd.w);
    }
    f32x4 cfr[4];
    #pragma unroll
    for (int c = 0; c < 4; c++) {
      cfr[c] = (f32x4){0.f, 0.f, 0.f, 0.f};
      cfr[c] = __builtin_amdgcn_mfma_f32_16x16x32_bf16(a0, bfr[c][0], cfr[c], 0, 0, 0);
      cfr[c] = __builtin_amdgcn_mfma_f32_16x16x32_bf16(a1, bfr[c][1], cfr[c], 0, 0, 0);
    }
    #pragma unroll
    for (int i = 0; i < 4; i++) {
      int row = r0 + quad * 4 + i;
      #pragma unroll
      for (int c = 0; c < 4; c++) hgb[(size_t)row * F + c * 16 + l15] = f2bf(cfr[c][i]);
      float ps = cfr[0][i] * as_l[0] + cfr[1][i] * as_l[1] + cfr[2][i] * as_l[2] + cfr[3][i] * as_l[3];
      float pd = cfr[0][i] * ad_l[0] + cfr[1][i] * ad_l[1] + cfr[2][i] * ad_l[2] + cfr[3][i] * ad_l[3];
      #pragma unroll
      for (int o = 1; o <= 8; o <<= 1) { ps += __shfl_xor(ps, o); pd += __shfl_xor(pd, o); }
      if (l15 == 0) { als[row] = ps; ald[row] = pd; }
    }
  }
}

// ---------------- fused softmax+SpMM, node-per-subgroup (natural order) ----------------
// MODE 0: write bf16 rows (layer 1).  MODE 1: fused readout dot with Wout + atomicAdd (layer 2).
template<int MODE>
__global__ __launch_bounds__(256) void k_spmm(const int* __restrict__ offs, const int* __restrict__ ssrc,
                                              const unsigned short* __restrict__ hgb,
                                              const float* __restrict__ als, const float* __restrict__ ald,
                                              const float* __restrict__ bias, const float* __restrict__ Wout,
                                              void* __restrict__ outp, int n) {
  int tid = threadIdx.x, lane = tid & 63, wv = tid >> 6;
  int g8 = lane >> 3, l8 = lane & 7;
  const uint4* hg4 = (const uint4*)hgb;
  float4 bl0 = ((const float4*)bias)[l8 * 2];
  float4 bl1 = ((const float4*)bias)[l8 * 2 + 1];

  int node = (blockIdx.x * 4 + wv) * 8 + g8;
  int cnode = min(node, n - 1);
  bool nodeok = node < n;
  int beg = offs[cnode];
  int deg = nodeok ? (offs[cnode + 1] - beg) : 0;
  int degc = max(deg - 1, 0);
  float aldv = ald[cnode];

  int dm = deg;
  #pragma unroll
  for (int o = 8; o <= 32; o <<= 1) dm = max(dm, __shfl_xor(dm, o));

  float s = 0.f;
  float acc[8];
  #pragma unroll
  for (int k = 0; k < 8; k++) acc[k] = 0.f;

  #pragma unroll 2
  for (int j = 0; j < dm; j++) {
    int jj = min(j, degc);
    int src = ssrc[beg + jj];
    float t = als[src] + aldv;
    t = fmaxf(t, 0.2f * t);                   // leaky_relu 0.2
    float ex = (j < deg) ? __expf(t) : 0.f;
    s += ex;
    uint4 u = hg4[(size_t)src * 8 + l8];
    acc[0] = fmaf(ex, __uint_as_float(u.x << 16), acc[0]);
    acc[1] = fmaf(ex, __uint_as_float(u.x & 0xffff0000u), acc[1]);
    acc[2] = fmaf(ex, __uint_as_float(u.y << 16), acc[2]);
    acc[3] = fmaf(ex, __uint_as_float(u.y & 0xffff0000u), acc[3]);
    acc[4] = fmaf(ex, __uint_as_float(u.z << 16), acc[4]);
    acc[5] = fmaf(ex, __uint_as_float(u.z & 0xffff0000u), acc[5]);
    acc[6] = fmaf(ex, __uint_as_float(u.w << 16), acc[6]);
    acc[7] = fmaf(ex, __uint_as_float(u.w & 0xffff0000u), acc[7]);
  }

  if (!nodeok) return;
  float iv = 1.f / (s + 1e-16f);
  float r[8];
  r[0] = fmaxf(fmaf(acc[0], iv, bl0.x), 0.f);
  r[1] = fmaxf(fmaf(acc[1], iv, bl0.y), 0.f);
  r[2] = fmaxf(fmaf(acc[2], iv, bl0.z), 0.f);
  r[3] = fmaxf(fmaf(acc[3], iv, bl0.w), 0.f);
  r[4] = fmaxf(fmaf(acc[4], iv, bl1.x), 0.f);
  r[5] = fmaxf(fmaf(acc[5], iv, bl1.y), 0.f);
  r[6] = fmaxf(fmaf(acc[6], iv, bl1.z), 0.f);
  r[7] = fmaxf(fmaf(acc[7], iv, bl1.w), 0.f);
  if constexpr (MODE == 0) {
    unsigned short p[8];
    #pragma unroll
    for (int k = 0; k < 8; k++) p[k] = f2bf(r[k]);
    ((uint4*)outp)[(size_t)node * 8 + l8] = *(const uint4*)p;
  } else {
    int grp = node / 20, slot = node - grp * 20;
    const float* wr = Wout + slot * F + l8 * 8;
    float dot = 0.f;
    #pragma unroll
    for (int k = 0; k < 8; k++) dot = fmaf(r[k], wr[k], dot);
    #pragma unroll
    for (int o = 1; o <= 4; o <<= 1) dot += __shfl_xor(dot, o);  // within subgroup
    if (l8 == 0) atomicAdd((float*)outp + grp, dot);
  }
}

// ---------------- launch ----------------
extern "C" void kernel_launch(void* const* d_in, const int* in_sizes, int n_in,
                              void* d_out, int out_size, void* d_ws, size_t ws_size,
                              hipStream_t stream) {
  const float* x   = (const float*)d_in[0];
  const int*   ei  = (const int*)d_in[1];
  const float* W1  = (const float*)d_in[2];
  const float* as1 = (const float*)d_in[3];
  const float* ad1 = (const float*)d_in[4];
  const float* b1  = (const float*)d_in[5];
  const float* W2  = (const float*)d_in[6];
  const float* as2 = (const float*)d_in[7];
  const float* ad2 = (const float*)d_in[8];
  const float* b2  = (const float*)d_in[9];
  const float* Wo  = (const float*)d_in[10];
  const float* bo  = (const float*)d_in[11];
  float* out = (float*)d_out;

  const int N = in_sizes[0] / F;
  const int E = in_sizes[1] / 2;
  const int* esrc = ei;
  const int* edst = ei + E;

  size_t off = 0;
  auto alloc = [&](size_t bytes) -> void* {
    void* p = (char*)d_ws + off;
    off += (bytes + 255) & ~(size_t)255;
    return p;
  };
  float* A    = (float*)alloc((size_t)N * F * 4);           // A1 bf16; CSR cnt/pos scratch aliases head
  unsigned short* hgb = (unsigned short*)alloc((size_t)N * F * 2);  // bf16 gemm outputs; binned aliases head
  float* als  = (float*)alloc((size_t)N * 4);
  float* ald  = (float*)alloc((size_t)N * 4);
  int* offs   = (int*)alloc((size_t)(N + 1) * 4);
  int* bsums  = (int*)alloc(8192);
  int* ssrc   = (int*)alloc((size_t)(E + N) * 4);           // CSR src lists
  uint4* wf   = (uint4*)alloc(16384);                       // packed W frags: 2 layers x 512 uint4
  (void)ws_size; (void)n_in; (void)out_size;

  const int NBLK = 256;
  const int NB = (N + NPB - 1) / NPB;
  const int CH = (E + NBLK - 1) / NBLK;
  const int FLAT = NB * NBLK;

  int* cntT = (int*)A;
  int* posT = (int*)((char*)A + ((size_t)FLAT * 4 + 1024));
  unsigned int* binned = (unsigned int*)hgb;

  int gF = (FLAT + 255) / 256;
  int NG = N / 20;

  // CSR build: bucketed counting sort (dst-major), self-loop at row head; +W prep; +out init
  k_bin_count<<<NBLK + 1, 256, 0, stream>>>(edst, cntT, E, CH, NBLK, NB, W1, W2, wf);
  k_scan1<<<gF, 256, 0, stream>>>(cntT, posT, bsums, FLAT);
  k_scan2<<<1, 256, 0, stream>>>(bsums, gF, out, bo, NG);
  k_bin_scatter<<<NBLK, 256, 0, stream>>>(esrc, edst, posT, bsums, binned, E, CH, NBLK, NB);
  k_bucket_csr<<<NB, 256, 0, stream>>>(binned, posT, bsums, ssrc, offs, N, NBLK, NB, E);

  int gSp = (N + 31) / 32;
  // layer 1
  k_gemm<false><<<2560, 256, 0, stream>>>(x, wf, as1, ad1, hgb, als, ald, N);
  k_spmm<0><<<gSp, 256, 0, stream>>>(offs, ssrc, hgb, als, ald, b1, nullptr, A, N);
  // layer 2 (reads bf16 A1) + fused readout
  k_gemm<true><<<2560, 256, 0, stream>>>(A, wf + 512, as2, ad2, hgb, als, ald, N);
  k_spmm<1><<<gSp, 256, 0, stream>>>(offs, ssrc, hgb, als, ald, b2, Wo, out, N);
}

// Round 12
// 309.778 us; speedup vs baseline: 1.0809x; 1.0318x over previous
//
#include <hip/hip_runtime.h>
#include <math.h>

#define F 64
#define NPB 160        // nodes per bucket
#define STAGE_CAP 6304 // staged CSR entries per bucket (mean ~2720, +60 sigma)

typedef __attribute__((ext_vector_type(8))) short bf16x8;
typedef __attribute__((ext_vector_type(4))) float f32x4;

__device__ inline unsigned short f2bf(float f) {
  unsigned int u = __float_as_uint(f);
  u += 0x7fffu + ((u >> 16) & 1u);   // round-to-nearest-even
  return (unsigned short)(u >> 16);
}

// ---------------- bucketed CSR build (+ W fragment prep in extra block) ----------------

__global__ __launch_bounds__(256) void k_bin_count(const int* __restrict__ edst, int* __restrict__ cntT,
                                                   int e, int ch, int nblk, int nb,
                                                   const float* __restrict__ W1, const float* __restrict__ W2,
                                                   uint4* __restrict__ wf) {
  __shared__ int h[1024];
  int k = blockIdx.x, tid = threadIdx.x;
  if (k == nblk) {
    // pack W1/W2 into MFMA B-fragment layout: wf[layer*512 + (c*2+kk)*64 + lane] = 8 bf16 (j=0..7)
    for (int i = tid; i < 1024; i += 256) {
      int layer = i >> 9, rem = i & 511;
      int cb = rem >> 6, lane = rem & 63;
      int c = cb >> 1, kk = cb & 1;
      int l15 = lane & 15, quad = lane >> 4;
      const float* W = layer ? W2 : W1;
      unsigned short p[8];
      #pragma unroll
      for (int j = 0; j < 8; j++) {
        int kd = kk * 32 + quad * 8 + j;
        p[j] = f2bf(W[kd * F + c * 16 + l15]);
      }
      wf[i] = *(const uint4*)p;
    }
    return;
  }
  for (int i = tid; i < nb; i += 256) h[i] = 0;
  __syncthreads();
  int beg = k * ch, end = min(e, beg + ch);
  for (int i = beg + tid; i < end; i += 256) atomicAdd(&h[edst[i] / NPB], 1);
  __syncthreads();
  for (int b = tid; b < nb; b += 256) cntT[b * nblk + k] = h[b];
}

// per-256-block exclusive scan; block totals to bsums (global offset = posT[i] + bsums[i>>8])
__global__ __launch_bounds__(256) void k_scan1(const int* __restrict__ counts, int* __restrict__ offs,
                                               int* __restrict__ bsums, int n) {
  int tid = threadIdx.x, lane = tid & 63, wv = tid >> 6;
  int i = blockIdx.x * 256 + tid;
  int v = (i < n) ? counts[i] : 0;
  int x = v;
  #pragma unroll
  for (int o = 1; o <= 32; o <<= 1) { int y = __shfl_up(x, o); if (lane >= o) x += y; }
  __shared__ int wsum[4];
  if (lane == 63) wsum[wv] = x;
  __syncthreads();
  int add = 0;
  for (int w = 0; w < wv; w++) add += wsum[w];
  int incl = x + add;
  if (i < n) offs[i] = incl - v;
  if (tid == 255) bsums[blockIdx.x] = incl;
}

// single-block scan of block sums; also initializes out[] = b_out
__global__ __launch_bounds__(256) void k_scan2(int* __restrict__ bs, int nb,
                                               float* __restrict__ out, const float* __restrict__ bo, int ng) {
  __shared__ int wsum[4];
  __shared__ int carry_sh;
  int tid = threadIdx.x, lane = tid & 63, wv = tid >> 6;
  float b0 = bo[0];
  for (int i = tid; i < ng; i += 256) out[i] = b0;
  if (tid == 0) carry_sh = 0;
  __syncthreads();
  for (int base = 0; base < nb; base += 256) {
    int i = base + tid;
    int v = (i < nb) ? bs[i] : 0;
    int x = v;
    #pragma unroll
    for (int o = 1; o <= 32; o <<= 1) { int y = __shfl_up(x, o); if (lane >= o) x += y; }
    if (lane == 63) wsum[wv] = x;
    __syncthreads();
    int add = 0;
    for (int w = 0; w < wv; w++) add += wsum[w];
    int incl = x + add;
    int carry = carry_sh;
    if (i < nb) bs[i] = incl - v + carry;
    __syncthreads();
    if (tid == 255) carry_sh = carry + incl;
    __syncthreads();
  }
}

// ---------------- MFMA GEMM body (shared by standalone and fused kernels) ----------------
template<bool IN_BF16>
__device__ __forceinline__ void gemm_body(const void* __restrict__ in, const uint4* __restrict__ wf,
                                          const float* __restrict__ avs, const float* __restrict__ avd,
                                          unsigned short* __restrict__ hgb, float* __restrict__ als,
                                          float* __restrict__ ald, int n, int bid, int nbl) {
  int tid = threadIdx.x, lane = tid & 63, wv = tid >> 6;
  int l15 = lane & 15, quad = lane >> 4;
  bf16x8 bfr[4][2];
  #pragma unroll
  for (int cb = 0; cb < 8; cb++) {
    uint4 u = wf[cb * 64 + lane];
    bfr[cb >> 1][cb & 1] = *(const bf16x8*)&u;
  }
  float as_l[4], ad_l[4];
  #pragma unroll
  for (int c = 0; c < 4; c++) { as_l[c] = avs[c * 16 + l15]; ad_l[c] = avd[c * 16 + l15]; }

  int nchunks = n >> 6;
  for (int chunk = bid; chunk < nchunks; chunk += nbl) {
    int r0 = (chunk << 6) + (wv << 4);
    bf16x8 a0, a1;
    if constexpr (IN_BF16) {
      const uint4* row4 = (const uint4*)((const unsigned short*)in + (size_t)(r0 + l15) * F);
      uint4 u0 = row4[quad];
      uint4 u1 = row4[quad + 4];
      a0 = *(const bf16x8*)&u0;
      a1 = *(const bf16x8*)&u1;
    } else {
      const float4* xr = (const float4*)((const float*)in + (size_t)(r0 + l15) * F + quad * 8);
      float4 xa = xr[0], xb = xr[1];
      float4 xc = xr[8], xd = xr[9];
      a0[0] = (short)f2bf(xa.x); a0[1] = (short)f2bf(xa.y); a0[2] = (short)f2bf(xa.z); a0[3] = (short)f2bf(xa.w);
      a0[4] = (short)f2bf(xb.x); a0[5] = (short)f2bf(xb.y); a0[6] = (short)f2bf(xb.z); a0[7] = (short)f2bf(xb.w);
      a1[0] = (short)f2bf(xc.x); a1[1] = (short)f2bf(xc.y); a1[2] = (short)f2bf(xc.z); a1[3] = (short)f2bf(xc.w);
      a1[4] = (short)f2bf(xd.x); a1[5] = (short)f2bf(xd.y); a1[6] = (short)f2bf(xd.z); a1[7] = (short)f2bf(xd.w);
    }
    f32x4 cfr[4];
    #pragma unroll
    for (int c = 0; c < 4; c++) {
      cfr[c] = (f32x4){0.f, 0.f, 0.f, 0.f};
      cfr[c] = __builtin_amdgcn_mfma_f32_16x16x32_bf16(a0, bfr[c][0], cfr[c], 0, 0, 0);
      cfr[c] = __builtin_amdgcn_mfma_f32_16x16x32_bf16(a1, bfr[c][1], cfr[c], 0, 0, 0);
    }
    #pragma unroll
    for (int i = 0; i < 4; i++) {
      int row = r0 + quad * 4 + i;
      #pragma unroll
      for (int c = 0; c < 4; c++) hgb[(size_t)row * F + c * 16 + l15] = f2bf(cfr[c][i]);
      float ps = cfr[0][i] * as_l[0] + cfr[1][i] * as_l[1] + cfr[2][i] * as_l[2] + cfr[3][i] * as_l[3];
      float pd = cfr[0][i] * ad_l[0] + cfr[1][i] * ad_l[1] + cfr[2][i] * ad_l[2] + cfr[3][i] * ad_l[3];
      #pragma unroll
      for (int o = 1; o <= 8; o <<= 1) { ps += __shfl_xor(ps, o); pd += __shfl_xor(pd, o); }
      if (l15 == 0) { als[row] = ps; ald[row] = pd; }
    }
  }
}

// ---------------- fused: bin_scatter (blocks < nblk) + layer-1 GEMM (remaining blocks) ----------------
__global__ __launch_bounds__(256) void k_scatter_gemm1(const int* __restrict__ esrc, const int* __restrict__ edst,
                                                       const int* __restrict__ posT, const int* __restrict__ bsums,
                                                       unsigned int* __restrict__ binned,
                                                       int e, int ch, int nblk, int nb,
                                                       const float* __restrict__ x, const uint4* __restrict__ wf,
                                                       const float* __restrict__ avs, const float* __restrict__ avd,
                                                       unsigned short* __restrict__ hgb, float* __restrict__ als,
                                                       float* __restrict__ ald, int n) {
  int k = blockIdx.x, tid = threadIdx.x;
  if (k < nblk) {
    __shared__ int cur[1024];
    for (int b = tid; b < nb; b += 256) {
      int idx = b * nblk + k;
      cur[b] = posT[idx] + bsums[idx >> 8];
    }
    __syncthreads();
    int beg = k * ch, end = min(e, beg + ch);
    for (int i = beg + tid; i < end; i += 256) {
      int d = edst[i];
      int b = d / NPB;
      unsigned int ld = (unsigned int)(d - b * NPB);
      int p = atomicAdd(&cur[b], 1);
      binned[p] = (unsigned int)esrc[i] | (ld << 24);
    }
    return;
  }
  gemm_body<false>(x, wf, avs, avd, hgb, als, ald, n, k - nblk, (int)gridDim.x - nblk);
}

__global__ __launch_bounds__(256) void k_gemm2(const unsigned short* __restrict__ in, const uint4* __restrict__ wf,
                                               const float* __restrict__ avs, const float* __restrict__ avd,
                                               unsigned short* __restrict__ hgb, float* __restrict__ als,
                                               float* __restrict__ ald, int n) {
  gemm_body<true>(in, wf, avs, avd, hgb, als, ald, n, blockIdx.x, gridDim.x);
}

// one block per bucket: build CSR rows (self-loop at row head), emit ssrc + offs
__global__ __launch_bounds__(256) void k_bucket_csr(const unsigned int* __restrict__ binned,
                                                    const int* __restrict__ posT, const int* __restrict__ bsums,
                                                    int* __restrict__ ssrc, int* __restrict__ offs,
                                                    int n, int nblk, int nb, int e) {
  __shared__ int ncnt[NPB];
  __shared__ int noff[NPB];
  __shared__ int cur[NPB];
  __shared__ int sc[256];
  __shared__ int stage[STAGE_CAP];
  int b = blockIdx.x, tid = threadIdx.x;
  int node0 = b * NPB;
  int nn = min(NPB, n - node0);
  int i0 = b * nblk;
  int ebeg = posT[i0] + bsums[i0 >> 8];
  int eend;
  if (b == nb - 1) eend = e;
  else { int i1 = (b + 1) * nblk; eend = posT[i1] + bsums[i1 >> 8]; }
  int ecnt = eend - ebeg;
  for (int i = tid; i < NPB; i += 256) ncnt[i] = 0;
  __syncthreads();
  for (int i = tid; i < ecnt; i += 256) { unsigned int v = binned[ebeg + i]; atomicAdd(&ncnt[v >> 24], 1); }
  __syncthreads();
  int x = (tid < nn) ? ncnt[tid] + 1 : 0;
  sc[tid] = x;
  __syncthreads();
  #pragma unroll
  for (int o = 1; o < 256; o <<= 1) {
    int y = (tid >= o) ? sc[tid - o] : 0;
    __syncthreads();
    sc[tid] += y;
    __syncthreads();
  }
  if (tid < nn) noff[tid] = sc[tid] - x;
  __syncthreads();
  int tot = ecnt + nn;
  int outbase = ebeg + node0;
  bool staged = (tot <= STAGE_CAP);
  if (tid < nn) {
    cur[tid] = noff[tid] + 1;
    offs[node0 + tid] = outbase + noff[tid];
    if (staged) stage[noff[tid]] = node0 + tid;
    else        ssrc[outbase + noff[tid]] = node0 + tid;
  }
  __syncthreads();
  if (staged) {
    for (int i = tid; i < ecnt; i += 256) {
      unsigned int v = binned[ebeg + i];
      int p = atomicAdd(&cur[v >> 24], 1);
      stage[p] = (int)(v & 0xFFFFFFu);
    }
    __syncthreads();
    for (int i = tid; i < tot; i += 256) ssrc[outbase + i] = stage[i];
  } else {
    for (int i = tid; i < ecnt; i += 256) {
      unsigned int v = binned[ebeg + i];
      int p = atomicAdd(&cur[v >> 24], 1);
      ssrc[outbase + p] = (int)(v & 0xFFFFFFu);
    }
  }
  if (b == 0 && tid == 0) offs[n] = e + n;
}

// ---------------- fused softmax+SpMM, node-per-subgroup ----------------
// MODE 0: write bf16 rows (layer 1).
// MODE 1: fused readout — per-node dot with Wout, LDS-aggregated per block (<=3 groups), <=3 global atomics.
template<int MODE>
__global__ __launch_bounds__(256) void k_spmm(const int* __restrict__ offs, const int* __restrict__ ssrc,
                                              const unsigned short* __restrict__ hgb,
                                              const float* __restrict__ als, const float* __restrict__ ald,
                                              const float* __restrict__ bias, const float* __restrict__ Wout,
                                              void* __restrict__ outp, int n) {
  int tid = threadIdx.x, lane = tid & 63, wv = tid >> 6;
  int g8 = lane >> 3, l8 = lane & 7;
  const uint4* hg4 = (const uint4*)hgb;
  float4 bl0 = ((const float4*)bias)[l8 * 2];
  float4 bl1 = ((const float4*)bias)[l8 * 2 + 1];

  __shared__ float gsl[3];   // MODE 1 group partials
  if (MODE == 1 && tid < 3) gsl[tid] = 0.f;

  int node = (blockIdx.x * 4 + wv) * 8 + g8;
  int cnode = min(node, n - 1);
  bool nodeok = node < n;
  int beg = offs[cnode];
  int deg = nodeok ? (offs[cnode + 1] - beg) : 0;
  int degc = max(deg - 1, 0);
  float aldv = ald[cnode];

  int dm = deg;
  #pragma unroll
  for (int o = 8; o <= 32; o <<= 1) dm = max(dm, __shfl_xor(dm, o));

  float s = 0.f;
  float acc[8];
  #pragma unroll
  for (int k = 0; k < 8; k++) acc[k] = 0.f;

  #pragma unroll 2
  for (int j = 0; j < dm; j++) {
    int jj = min(j, degc);
    int src = ssrc[beg + jj];
    float t = als[src] + aldv;
    t = fmaxf(t, 0.2f * t);                   // leaky_relu 0.2
    float ex = (j < deg) ? __expf(t) : 0.f;
    s += ex;
    uint4 u = hg4[(size_t)src * 8 + l8];
    acc[0] = fmaf(ex, __uint_as_float(u.x << 16), acc[0]);
    acc[1] = fmaf(ex, __uint_as_float(u.x & 0xffff0000u), acc[1]);
    acc[2] = fmaf(ex, __uint_as_float(u.y << 16), acc[2]);
    acc[3] = fmaf(ex, __uint_as_float(u.y & 0xffff0000u), acc[3]);
    acc[4] = fmaf(ex, __uint_as_float(u.z << 16), acc[4]);
    acc[5] = fmaf(ex, __uint_as_float(u.z & 0xffff0000u), acc[5]);
    acc[6] = fmaf(ex, __uint_as_float(u.w << 16), acc[6]);
    acc[7] = fmaf(ex, __uint_as_float(u.w & 0xffff0000u), acc[7]);
  }

  float iv = 1.f / (s + 1e-16f);
  float r[8];
  r[0] = fmaxf(fmaf(acc[0], iv, bl0.x), 0.f);
  r[1] = fmaxf(fmaf(acc[1], iv, bl0.y), 0.f);
  r[2] = fmaxf(fmaf(acc[2], iv, bl0.z), 0.f);
  r[3] = fmaxf(fmaf(acc[3], iv, bl0.w), 0.f);
  r[4] = fmaxf(fmaf(acc[4], iv, bl1.x), 0.f);
  r[5] = fmaxf(fmaf(acc[5], iv, bl1.y), 0.f);
  r[6] = fmaxf(fmaf(acc[6], iv, bl1.z), 0.f);
  r[7] = fmaxf(fmaf(acc[7], iv, bl1.w), 0.f);

  if constexpr (MODE == 0) {
    if (!nodeok) return;
    unsigned short p[8];
    #pragma unroll
    for (int k = 0; k < 8; k++) p[k] = f2bf(r[k]);
    ((uint4*)outp)[(size_t)node * 8 + l8] = *(const uint4*)p;
  } else {
    int node0 = blockIdx.x * 32;
    int grp0 = node0 / 20;
    int grp = cnode / 20, slot = cnode - grp * 20;
    const float* wr = Wout + slot * F + l8 * 8;
    float dot = 0.f;
    #pragma unroll
    for (int k = 0; k < 8; k++) dot = fmaf(r[k], wr[k], dot);
    #pragma unroll
    for (int o = 1; o <= 4; o <<= 1) dot += __shfl_xor(dot, o);  // within subgroup
    __syncthreads();                       // gsl init visible
    if (nodeok && l8 == 0) atomicAdd(&gsl[grp - grp0], dot);
    __syncthreads();
    if (tid < 3) {
      float v = gsl[tid];
      if (v != 0.f) atomicAdd((float*)outp + grp0 + tid, v);
    }
  }
}

// ---------------- launch ----------------
extern "C" void kernel_launch(void* const* d_in, const int* in_sizes, int n_in,
                              void* d_out, int out_size, void* d_ws, size_t ws_size,
                              hipStream_t stream) {
  const float* x   = (const float*)d_in[0];
  const int*   ei  = (const int*)d_in[1];
  const float* W1  = (const float*)d_in[2];
  const float* as1 = (const float*)d_in[3];
  const float* ad1 = (const float*)d_in[4];
  const float* b1  = (const float*)d_in[5];
  const float* W2  = (const float*)d_in[6];
  const float* as2 = (const float*)d_in[7];
  const float* ad2 = (const float*)d_in[8];
  const float* b2  = (const float*)d_in[9];
  const float* Wo  = (const float*)d_in[10];
  const float* bo  = (const float*)d_in[11];
  float* out = (float*)d_out;

  const int N = in_sizes[0] / F;
  const int E = in_sizes[1] / 2;
  const int* esrc = ei;
  const int* edst = ei + E;

  size_t off = 0;
  auto alloc = [&](size_t bytes) -> void* {
    void* p = (char*)d_ws + off;
    off += (bytes + 255) & ~(size_t)255;
    return p;
  };
  float* A    = (float*)alloc((size_t)N * F * 4);           // A1 bf16; CSR cnt/pos/binned scratch aliases
  unsigned short* hgb = (unsigned short*)alloc((size_t)N * F * 2);  // bf16 gemm outputs
  float* als  = (float*)alloc((size_t)N * 4);
  float* ald  = (float*)alloc((size_t)N * 4);
  int* offs   = (int*)alloc((size_t)(N + 1) * 4);
  int* bsums  = (int*)alloc(8192);
  int* ssrc   = (int*)alloc((size_t)(E + N) * 4);           // CSR src lists
  uint4* wf   = (uint4*)alloc(16384);                       // packed W frags: 2 layers x 512 uint4
  (void)ws_size; (void)n_in; (void)out_size;

  const int NBLK = 256;
  const int NB = (N + NPB - 1) / NPB;
  const int CH = (E + NBLK - 1) / NBLK;
  const int FLAT = NB * NBLK;

  // CSR scratch all inside A (dead until spmm<0> writes it; binned must NOT alias hgb —
  // gemm1 writes hgb concurrently with bin_scatter in the fused launch)
  int* cntT = (int*)A;
  int* posT = (int*)((char*)A + ((size_t)FLAT * 4 + 1024));
  unsigned int* binned = (unsigned int*)((char*)A + (size_t)8 * 1024 * 1024);

  int gF = (FLAT + 255) / 256;
  int NG = N / 20;

  // CSR build + W prep + out init
  k_bin_count<<<NBLK + 1, 256, 0, stream>>>(edst, cntT, E, CH, NBLK, NB, W1, W2, wf);
  k_scan1<<<gF, 256, 0, stream>>>(cntT, posT, bsums, FLAT);
  k_scan2<<<1, 256, 0, stream>>>(bsums, gF, out, bo, NG);
  // fused: edge scatter (256 blocks) + layer-1 GEMM (2560 blocks)
  k_scatter_gemm1<<<NBLK + (N >> 6), 256, 0, stream>>>(esrc, edst, posT, bsums, binned, E, CH, NBLK, NB,
                                                       x, wf, as1, ad1, hgb, als, ald, N);
  k_bucket_csr<<<NB, 256, 0, stream>>>(binned, posT, bsums, ssrc, offs, N, NBLK, NB, E);

  int gSp = (N + 31) / 32;
  // layer 1 aggregation -> bf16 A1
  k_spmm<0><<<gSp, 256, 0, stream>>>(offs, ssrc, hgb, als, ald, b1, nullptr, A, N);
  // layer 2 GEMM (reads bf16 A1)
  k_gemm2<<<(N >> 6), 256, 0, stream>>>((const unsigned short*)A, wf + 512, as2, ad2, hgb, als, ald, N);
  // layer 2 aggregation + fused readout
  k_spmm<1><<<gSp, 256, 0, stream>>>(offs, ssrc, hgb, als, ald, b2, Wo, out, N);
}